// Round 1
// baseline (522.983 us; speedup 1.0000x reference)
//
#include <hip/hip_runtime.h>
#include <math.h>

#define NB 8
#define NP 4096
#define TOPK 10
#define KNB 9
#define QPB 64
#define SLC 4
#define CPS (NP / SLC)      // 1024 candidates per slice
#define NCHUNK (NP / QPB)   // 64 chunks per batch

#define FINF 3.0e38f
#define PI_F 3.14159274101257324f

__global__ __launch_bounds__(256, 2)
void repsurf_fused(const float* __restrict__ x,
                   const float* __restrict__ cw1,
                   const float* __restrict__ bg1, const float* __restrict__ bb1,
                   const float* __restrict__ bm1, const float* __restrict__ bv1,
                   const float* __restrict__ cw2, const float* __restrict__ cb2,
                   const float* __restrict__ bg2, const float* __restrict__ bb2,
                   const float* __restrict__ bm2, const float* __restrict__ bv2,
                   const float* __restrict__ cw3, const float* __restrict__ cb3,
                   float* __restrict__ out)
{
    __shared__ __align__(16) float sx[NP];
    __shared__ __align__(16) float sy[NP];
    __shared__ __align__(16) float sz[NP];
    __shared__ float md[QPB * 41];   // stride 41: gcd(41,32)=1, conflict-free
    __shared__ int   mi[QPB * 41];
    __shared__ __align__(16) float sW1[9 * 12];  // rows padded to 12 for float4 reads
    __shared__ __align__(16) float sW2[9 * 12];
    __shared__ __align__(16) float sW3[9 * 12];
    __shared__ float sSh1[9], sSh2[9], sSh3[9];

    const int t  = threadIdx.x;
    const int b  = blockIdx.x >> 6;    // NCHUNK == 64
    const int qc = blockIdx.x & 63;

    // ---- stage points for this batch into LDS (coalesced) ----
    const float* xb = x + (size_t)b * 3 * NP;
    for (int i = t; i < 3 * NP; i += 256) {
        float v = xb[i];
        int c = i >> 12;          // channel
        int p = i & (NP - 1);     // point index
        if (c == 0) sx[p] = v;
        else if (c == 1) sy[p] = v;
        else sz[p] = v;
    }
    // ---- fold BN into conv weights, stage in LDS ----
    if (t < 108) {
        int o = t / 12, c = t % 12;
        float w1v = 0.f, w2v = 0.f, w3v = 0.f;
        if (c < 9) {
            float iv1 = bg1[o] * rsqrtf(bv1[o] + 1e-5f);
            float iv2 = bg2[o] * rsqrtf(bv2[o] + 1e-5f);
            w1v = cw1[o * 9 + c] * iv1;
            w2v = cw2[o * 9 + c] * iv2;
            w3v = cw3[o * 9 + c];
        }
        sW1[t] = w1v; sW2[t] = w2v; sW3[t] = w3v;
        if (t < 9) {
            float iv1 = bg1[t] * rsqrtf(bv1[t] + 1e-5f);
            float iv2 = bg2[t] * rsqrtf(bv2[t] + 1e-5f);
            sSh1[t] = bb1[t] - bm1[t] * iv1;
            sSh2[t] = cb2[t] * iv2 + bb2[t] - bm2[t] * iv2;
            sSh3[t] = cb3[t];
        }
    }
    __syncthreads();

    // ---- phase 1: per-thread top-10 over this thread's candidate slice ----
    const int q  = t & (QPB - 1);
    const int s  = t >> 6;
    const int qi = qc * QPB + q;
    const float qx = sx[qi], qy = sy[qi], qz = sz[qi];

    float dk[TOPK];
    int   ik[TOPK];
#pragma unroll
    for (int j = 0; j < TOPK; ++j) { dk[j] = FINF; ik[j] = 0x7fffffff; }

    const float4* sx4 = (const float4*)sx;
    const float4* sy4 = (const float4*)sy;
    const float4* sz4 = (const float4*)sz;
    const int b4 = s * (CPS / 4);

#define DOCAND(PX, PY, PZ, MIDX) do { \
        float dx = (PX) - qx, dy = (PY) - qy, dz = (PZ) - qz; \
        float d = fmaf(dx, dx, fmaf(dy, dy, dz * dz)); \
        if (d < dk[TOPK - 1]) { \
            dk[TOPK - 1] = d; ik[TOPK - 1] = (MIDX); \
            _Pragma("unroll") \
            for (int jj = TOPK - 1; jj > 0; --jj) { \
                if (dk[jj] < dk[jj - 1]) { \
                    float td = dk[jj]; dk[jj] = dk[jj - 1]; dk[jj - 1] = td; \
                    int ti = ik[jj]; ik[jj] = ik[jj - 1]; ik[jj - 1] = ti; } \
            } \
        } } while (0)

    for (int mm = 0; mm < CPS / 4; ++mm) {
        float4 X = sx4[b4 + mm];
        float4 Y = sy4[b4 + mm];
        float4 Z = sz4[b4 + mm];
        const int m0 = s * CPS + mm * 4;
        DOCAND(X.x, Y.x, Z.x, m0 + 0);
        DOCAND(X.y, Y.y, Z.y, m0 + 1);
        DOCAND(X.z, Y.z, Z.z, m0 + 2);
        DOCAND(X.w, Y.w, Z.w, m0 + 3);
    }

    const int qb = q * 41;
#pragma unroll
    for (int j = 0; j < TOPK; ++j) {
        md[qb + s * TOPK + j] = dk[j];
        mi[qb + s * TOPK + j] = ik[j];
    }
    __syncthreads();

    // ---- phase 2: merge + geometry + MLP (one wave per block) ----
    if (t < QPB) {
        // 4-way merge of sorted lists, tie-break by index (== lax.top_k order)
        int ni[KNB];
        int p0 = 0, p1 = 0, p2 = 0, p3 = 0;
#pragma unroll
        for (int j = 0; j < TOPK; ++j) {
            float d0 = (p0 < TOPK) ? md[qb + p0]            : FINF;
            int   i0 = (p0 < TOPK) ? mi[qb + p0]            : 0x7fffffff;
            float d1 = (p1 < TOPK) ? md[qb + TOPK + p1]     : FINF;
            int   i1 = (p1 < TOPK) ? mi[qb + TOPK + p1]     : 0x7fffffff;
            float d2 = (p2 < TOPK) ? md[qb + 2 * TOPK + p2] : FINF;
            int   i2 = (p2 < TOPK) ? mi[qb + 2 * TOPK + p2] : 0x7fffffff;
            float d3 = (p3 < TOPK) ? md[qb + 3 * TOPK + p3] : FINF;
            int   i3 = (p3 < TOPK) ? mi[qb + 3 * TOPK + p3] : 0x7fffffff;
            bool w01 = (d0 < d1) || (d0 == d1 && i0 < i1);
            float dA = w01 ? d0 : d1; int iA = w01 ? i0 : i1; int sA = w01 ? 0 : 1;
            bool w23 = (d2 < d3) || (d2 == d3 && i2 < i3);
            float dB = w23 ? d2 : d3; int iB = w23 ? i2 : i3; int sB = w23 ? 2 : 3;
            bool wA = (dA < dB) || (dA == dB && iA < iB);
            int iw = wA ? iA : iB; int sw = wA ? sA : sB;
            if (j > 0) ni[j - 1] = iw;   // drop entry 0 == self (d = 0)
            p0 += (sw == 0); p1 += (sw == 1); p2 += (sw == 2); p3 += (sw == 3);
        }

        // gather relative neighbor coords + azimuth key
        float gx[KNB], gy[KNB], gz[KNB], kk[KNB];
#pragma unroll
        for (int j = 0; j < KNB; ++j) {
            int id = ni[j];
            gx[j] = sx[id] - qx;
            gy[j] = sy[id] - qy;
            gz[j] = sz[id] - qz;
            kk[j] = atan2f(gy[j], gx[j]);   // monotone in reference phi
        }
        // stable bubble sort (matches stable argsort; strict < keeps ties in order)
#pragma unroll
        for (int pass = 0; pass < KNB - 1; ++pass) {
#pragma unroll
            for (int j = 0; j < KNB - 1 - pass; ++j) {
                if (kk[j + 1] < kk[j]) {
                    float tv;
                    tv = kk[j]; kk[j] = kk[j + 1]; kk[j + 1] = tv;
                    tv = gx[j]; gx[j] = gx[j + 1]; gx[j + 1] = tv;
                    tv = gy[j]; gy[j] = gy[j + 1]; gy[j + 1] = tv;
                    tv = gz[j]; gz[j] = gz[j + 1]; gz[j + 1] = tv;
                }
            }
        }

        // umbrella normals (cross(v1, v2), normalized, sign from un[0].x)
        float ux[KNB], uy[KNB], uz[KNB];
#pragma unroll
        for (int j = 0; j < KNB; ++j) {
            int j2 = (j + 1 == KNB) ? 0 : j + 1;
            float nx_ = gy[j] * gz[j2] - gz[j] * gy[j2];
            float ny_ = gz[j] * gx[j2] - gx[j] * gz[j2];
            float nz_ = gx[j] * gy[j2] - gy[j] * gx[j2];
            float l = sqrtf(nx_ * nx_ + ny_ * ny_ + nz_ * nz_);
            float inv = 1.0f / fmaxf(l, 1e-10f);
            ux[j] = nx_ * inv; uy[j] = ny_ * inv; uz[j] = nz_ * inv;
        }
        float sgn = (ux[0] > 0.0f) ? 1.0f : -1.0f;

        const float4* W1v = (const float4*)sW1;
        const float4* W2v = (const float4*)sW2;
        const float4* W3v = (const float4*)sW3;

#define DOT9(WV, O, V) ( \
        (WV)[(O)*3+0].x * (V)[0] + (WV)[(O)*3+0].y * (V)[1] + \
        (WV)[(O)*3+0].z * (V)[2] + (WV)[(O)*3+0].w * (V)[3] + \
        (WV)[(O)*3+1].x * (V)[4] + (WV)[(O)*3+1].y * (V)[5] + \
        (WV)[(O)*3+1].z * (V)[6] + (WV)[(O)*3+1].w * (V)[7] + \
        (WV)[(O)*3+2].x * (V)[8] )

        float acc[9];
#pragma unroll
        for (int o = 0; o < 9; ++o) acc[o] = 0.0f;

#pragma unroll
        for (int j = 0; j < KNB; ++j) {
            int j2 = (j + 1 == KNB) ? 0 : j + 1;
            float cx = (gx[j] + gx[j2]) * (1.0f / 3.0f);
            float cy = (gy[j] + gy[j2]) * (1.0f / 3.0f);
            float cz = (gz[j] + gz[j2]) * (1.0f / 3.0f);
            float rho = sqrtf(cx * cx + cy * cy + cz * cz);
            float rs  = fmaxf(rho, 1e-8f);
            float ct  = fminf(fmaxf(cz / rs, -1.0f), 1.0f);
            float th  = acosf(ct) / PI_F;
            float ph  = atan2f(cy, cx) / (2.0f * PI_F) + 0.5f;
            float f[9]  = {cx, cy, cz, rho, th, ph, ux[j] * sgn, uy[j] * sgn, uz[j] * sgn};
            float t1[9], t2[9];
#pragma unroll
            for (int o = 0; o < 9; ++o)
                t1[o] = fmaxf(DOT9(W1v, o, f) + sSh1[o], 0.0f);
#pragma unroll
            for (int o = 0; o < 9; ++o)
                t2[o] = fmaxf(DOT9(W2v, o, t1) + sSh2[o], 0.0f);
#pragma unroll
            for (int o = 0; o < 9; ++o)
                acc[o] += DOT9(W3v, o, t2);
        }

        float* ob = out + (size_t)b * 9 * NP;
#pragma unroll
        for (int o = 0; o < 9; ++o)
            ob[o * NP + qi] = acc[o] + 9.0f * sSh3[o];   // conv3 bias summed over 9 ring slots
    }
}

extern "C" void kernel_launch(void* const* d_in, const int* in_sizes, int n_in,
                              void* d_out, int out_size, void* d_ws, size_t ws_size,
                              hipStream_t stream) {
    const float* x   = (const float*)d_in[0];
    const float* cw1 = (const float*)d_in[1];
    const float* bg1 = (const float*)d_in[2];
    const float* bb1 = (const float*)d_in[3];
    const float* bm1 = (const float*)d_in[4];
    const float* bv1 = (const float*)d_in[5];
    const float* cw2 = (const float*)d_in[6];
    const float* cb2 = (const float*)d_in[7];
    const float* bg2 = (const float*)d_in[8];
    const float* bb2 = (const float*)d_in[9];
    const float* bm2 = (const float*)d_in[10];
    const float* bv2 = (const float*)d_in[11];
    const float* cw3 = (const float*)d_in[12];
    const float* cb3 = (const float*)d_in[13];
    float* out = (float*)d_out;

    hipLaunchKernelGGL(repsurf_fused, dim3(NB * NCHUNK), dim3(256), 0, stream,
                       x, cw1, bg1, bb1, bm1, bv1, cw2, cb2, bg2, bb2, bm2, bv2,
                       cw3, cb3, out);
}

// Round 2
// 236.307 us; speedup vs baseline: 2.2132x; 2.2132x over previous
//
#include <hip/hip_runtime.h>
#include <math.h>

#define NB 8
#define NP 4096
#define TOPK 10
#define KNB 9
#define QPB 16              // queries per block
#define SLC 8               // candidate slices per query (all in-block)
#define NT 4                // candidate tiles
#define TPTS 1024           // points per tile
#define QPT (TPTS / SLC)    // 128 candidates per (tile, slice)
#define QW 132              // padded quarter stride (floats): 4s bank stagger
#define CHW (SLC * QW)      // 1056 floats per channel in tile
#define MST (SLC * TOPK + 1)  // 81: merge row stride, gcd(81,32)=1

#define FINF 3.0e38f
#define PI_F 3.14159274101257324f

__global__ __launch_bounds__(128, 4)
void repsurf_fused(const float* __restrict__ x,
                   const float* __restrict__ cw1,
                   const float* __restrict__ bg1, const float* __restrict__ bb1,
                   const float* __restrict__ bm1, const float* __restrict__ bv1,
                   const float* __restrict__ cw2, const float* __restrict__ cb2,
                   const float* __restrict__ bg2, const float* __restrict__ bb2,
                   const float* __restrict__ bm2, const float* __restrict__ bv2,
                   const float* __restrict__ cw3, const float* __restrict__ cb3,
                   float* __restrict__ out)
{
    // union: phase-1 candidate tile (3*CHW = 3168 floats) | phase-2 merge lists
    __shared__ __align__(16) float uS[3 * CHW];
    float* md   = uS;                       // [QPB][MST] floats
    int*   mi   = (int*)(uS + QPB * MST);   // [QPB][MST] ints
    float* tile = uS;

    __shared__ __align__(16) float sW1[9 * 12];
    __shared__ __align__(16) float sW2[9 * 12];
    __shared__ __align__(16) float sW3[9 * 12];
    __shared__ float sSh1[9], sSh2[9], sSh3[9];

    const int t  = threadIdx.x;
    const int b  = blockIdx.x >> 8;          // 256 chunks per batch
    const int qc = blockIdx.x & 255;
    const float* xb = x + (size_t)b * 3 * NP;

    // ---- fold BN into conv weights (before first barrier) ----
    if (t < 108) {
        int o = t / 12, c = t % 12;
        float w1v = 0.f, w2v = 0.f, w3v = 0.f;
        if (c < 9) {
            float iv1 = bg1[o] * rsqrtf(bv1[o] + 1e-5f);
            float iv2 = bg2[o] * rsqrtf(bv2[o] + 1e-5f);
            w1v = cw1[o * 9 + c] * iv1;
            w2v = cw2[o * 9 + c] * iv2;
            w3v = cw3[o * 9 + c];
        }
        sW1[t] = w1v; sW2[t] = w2v; sW3[t] = w3v;
        if (t < 9) {
            float iv1 = bg1[t] * rsqrtf(bv1[t] + 1e-5f);
            float iv2 = bg2[t] * rsqrtf(bv2[t] + 1e-5f);
            sSh1[t] = bb1[t] - bm1[t] * iv1;
            sSh2[t] = cb2[t] * iv2 + bb2[t] - bm2[t] * iv2;
            sSh3[t] = cb3[t];
        }
    }

    const int q  = t & (QPB - 1);
    const int s  = t >> 4;                   // slice 0..7 (wave-quartered)
    const int qi = qc * QPB + q;
    const float qx = xb[qi], qy = xb[NP + qi], qz = xb[2 * NP + qi];

    float dk[TOPK];
    int   ik[TOPK];
#pragma unroll
    for (int j = 0; j < TOPK; ++j) { dk[j] = FINF; ik[j] = 0x7fffffff; }

    // 2-deep register push buffer (deferred insertion)
    float db0 = 0.f, db1 = 0.f;
    int   ib0 = 0,   ib1 = 0,   cnt = 0;

#define INSERTE(DD, II) do { \
        float _d = (DD); int _i = (II); \
        if (_d < dk[TOPK - 1]) { \
            dk[TOPK - 1] = _d; ik[TOPK - 1] = _i; \
            _Pragma("unroll") \
            for (int jj = TOPK - 1; jj > 0; --jj) { \
                if (dk[jj] < dk[jj - 1]) { \
                    float td = dk[jj]; dk[jj] = dk[jj - 1]; dk[jj - 1] = td; \
                    int ti = ik[jj]; ik[jj] = ik[jj - 1]; ik[jj - 1] = ti; } \
            } \
        } } while (0)

#define DRAIN() do { \
        if (cnt >= 2) INSERTE(db1, ib1); \
        if (cnt >= 1) INSERTE(db0, ib0); \
        cnt = 0; } while (0)

#define DOCAND(PX, PY, PZ, MIDX) do { \
        float dx = (PX) - qx, dy = (PY) - qy, dz = (PZ) - qz; \
        float d = fmaf(dx, dx, fmaf(dy, dy, dz * dz)); \
        if (d < dk[TOPK - 1]) { db1 = db0; ib1 = ib0; db0 = d; ib0 = (MIDX); cnt++; } \
        if (__any(cnt >= 2)) DRAIN(); \
    } while (0)

    // ---- phase 1: tiled candidate scan ----
    for (int tt = 0; tt < NT; ++tt) {
        // stage tile tt: 768 float4, quarter-staggered layout
        const float* src0 = xb + tt * TPTS;
#pragma unroll
        for (int r = 0; r < 6; ++r) {
            int f = r * 128 + t;             // float4 index 0..767
            int c = f >> 8;                  // channel
            int o = f & 255;                 // float4 within channel
            float4 v = *(const float4*)(src0 + c * NP + o * 4);
            ((float4*)tile)[c * 264 + (o >> 5) * 33 + (o & 31)] = v;
        }
        __syncthreads();

        const float4* tx4 = (const float4*)tile + s * 33;
        const float4* ty4 = (const float4*)tile + 264 + s * 33;
        const float4* tz4 = (const float4*)tile + 528 + s * 33;
        const int base_idx = tt * TPTS + s * QPT;
        for (int mm = 0; mm < QPT / 4; ++mm) {
            float4 X = tx4[mm];
            float4 Y = ty4[mm];
            float4 Z = tz4[mm];
            const int m0 = base_idx + mm * 4;
            DOCAND(X.x, Y.x, Z.x, m0 + 0);
            DOCAND(X.y, Y.y, Z.y, m0 + 1);
            DOCAND(X.z, Y.z, Z.z, m0 + 2);
            DOCAND(X.w, Y.w, Z.w, m0 + 3);
        }
        __syncthreads();
    }
    DRAIN();

    // ---- write per-(query, slice) sorted top-10 to merge space ----
    const int qb = q * MST;
#pragma unroll
    for (int j = 0; j < TOPK; ++j) {
        md[qb + s * TOPK + j] = dk[j];
        mi[qb + s * TOPK + j] = ik[j];
    }
    __syncthreads();

    // ---- phase 2: 8-way merge + geometry + MLP ----
    if (t < QPB) {
        int ni[KNB];
        int p0 = 0, p1 = 0, p2 = 0, p3 = 0, p4 = 0, p5 = 0, p6 = 0, p7 = 0;
#pragma unroll
        for (int j = 0; j < TOPK; ++j) {
#define GETH(K) float d##K; int i##K; \
            { int pk = p##K; \
              if (pk < TOPK) { d##K = md[qb + K * TOPK + pk]; i##K = mi[qb + K * TOPK + pk]; } \
              else { d##K = FINF; i##K = 0x7fffffff; } }
            GETH(0) GETH(1) GETH(2) GETH(3) GETH(4) GETH(5) GETH(6) GETH(7)
#undef GETH
#define WIN(DA, IA, SA, DB, IB, SB, DO_, IO_, SO_) \
            bool w_##SO_ = ((DA) < (DB)) || ((DA) == (DB) && (IA) < (IB)); \
            float DO_ = w_##SO_ ? (DA) : (DB); \
            int IO_ = w_##SO_ ? (IA) : (IB); \
            int SO_ = w_##SO_ ? (SA) : (SB);
            WIN(d0, i0, 0, d1, i1, 1, dA, iA, sA)
            WIN(d2, i2, 2, d3, i3, 3, dB, iB, sB)
            WIN(d4, i4, 4, d5, i5, 5, dC, iC, sC)
            WIN(d6, i6, 6, d7, i7, 7, dD, iD, sD)
            WIN(dA, iA, sA, dB, iB, sB, dE, iE, sE)
            WIN(dC, iC, sC, dD, iD, sD, dF, iF, sF)
            WIN(dE, iE, sE, dF, iF, sF, dG, iG, sw)
            (void)dG; (void)iG;
#undef WIN
            if (j > 0) ni[j - 1] = iG;      // drop entry 0 == self
            p0 += (sw == 0); p1 += (sw == 1); p2 += (sw == 2); p3 += (sw == 3);
            p4 += (sw == 4); p5 += (sw == 5); p6 += (sw == 6); p7 += (sw == 7);
        }

        // gather relative neighbor coords (global; L1/L2-resident) + azimuth key
        float gx[KNB], gy[KNB], gz[KNB], kk[KNB];
#pragma unroll
        for (int j = 0; j < KNB; ++j) {
            int id = ni[j];
            gx[j] = xb[id] - qx;
            gy[j] = xb[NP + id] - qy;
            gz[j] = xb[2 * NP + id] - qz;
            kk[j] = atan2f(gy[j], gx[j]);
        }
        // stable bubble sort by azimuth
#pragma unroll
        for (int pass = 0; pass < KNB - 1; ++pass) {
#pragma unroll
            for (int j = 0; j < KNB - 1 - pass; ++j) {
                if (kk[j + 1] < kk[j]) {
                    float tv;
                    tv = kk[j]; kk[j] = kk[j + 1]; kk[j + 1] = tv;
                    tv = gx[j]; gx[j] = gx[j + 1]; gx[j + 1] = tv;
                    tv = gy[j]; gy[j] = gy[j + 1]; gy[j + 1] = tv;
                    tv = gz[j]; gz[j] = gz[j + 1]; gz[j + 1] = tv;
                }
            }
        }

        // umbrella normals
        float ux[KNB], uy[KNB], uz[KNB];
#pragma unroll
        for (int j = 0; j < KNB; ++j) {
            int j2 = (j + 1 == KNB) ? 0 : j + 1;
            float nx_ = gy[j] * gz[j2] - gz[j] * gy[j2];
            float ny_ = gz[j] * gx[j2] - gx[j] * gz[j2];
            float nz_ = gx[j] * gy[j2] - gy[j] * gx[j2];
            float l = sqrtf(nx_ * nx_ + ny_ * ny_ + nz_ * nz_);
            float inv = 1.0f / fmaxf(l, 1e-10f);
            ux[j] = nx_ * inv; uy[j] = ny_ * inv; uz[j] = nz_ * inv;
        }
        float sgn = (ux[0] > 0.0f) ? 1.0f : -1.0f;

        const float4* W1v = (const float4*)sW1;
        const float4* W2v = (const float4*)sW2;
        const float4* W3v = (const float4*)sW3;

#define DOT9(WV, O, V) ( \
        (WV)[(O)*3+0].x * (V)[0] + (WV)[(O)*3+0].y * (V)[1] + \
        (WV)[(O)*3+0].z * (V)[2] + (WV)[(O)*3+0].w * (V)[3] + \
        (WV)[(O)*3+1].x * (V)[4] + (WV)[(O)*3+1].y * (V)[5] + \
        (WV)[(O)*3+1].z * (V)[6] + (WV)[(O)*3+1].w * (V)[7] + \
        (WV)[(O)*3+2].x * (V)[8] )

        float acc[9];
#pragma unroll
        for (int o = 0; o < 9; ++o) acc[o] = 0.0f;

#pragma unroll
        for (int j = 0; j < KNB; ++j) {
            int j2 = (j + 1 == KNB) ? 0 : j + 1;
            float cx = (gx[j] + gx[j2]) * (1.0f / 3.0f);
            float cy = (gy[j] + gy[j2]) * (1.0f / 3.0f);
            float cz = (gz[j] + gz[j2]) * (1.0f / 3.0f);
            float rho = sqrtf(cx * cx + cy * cy + cz * cz);
            float rs  = fmaxf(rho, 1e-8f);
            float ct  = fminf(fmaxf(cz / rs, -1.0f), 1.0f);
            float th  = acosf(ct) / PI_F;
            float ph  = atan2f(cy, cx) / (2.0f * PI_F) + 0.5f;
            float f[9]  = {cx, cy, cz, rho, th, ph, ux[j] * sgn, uy[j] * sgn, uz[j] * sgn};
            float t1[9], t2[9];
#pragma unroll
            for (int o = 0; o < 9; ++o)
                t1[o] = fmaxf(DOT9(W1v, o, f) + sSh1[o], 0.0f);
#pragma unroll
            for (int o = 0; o < 9; ++o)
                t2[o] = fmaxf(DOT9(W2v, o, t1) + sSh2[o], 0.0f);
#pragma unroll
            for (int o = 0; o < 9; ++o)
                acc[o] += DOT9(W3v, o, t2);
        }

        float* ob = out + (size_t)b * 9 * NP;
#pragma unroll
        for (int o = 0; o < 9; ++o)
            ob[o * NP + qi] = acc[o] + 9.0f * sSh3[o];
    }
}

extern "C" void kernel_launch(void* const* d_in, const int* in_sizes, int n_in,
                              void* d_out, int out_size, void* d_ws, size_t ws_size,
                              hipStream_t stream) {
    const float* x   = (const float*)d_in[0];
    const float* cw1 = (const float*)d_in[1];
    const float* bg1 = (const float*)d_in[2];
    const float* bb1 = (const float*)d_in[3];
    const float* bm1 = (const float*)d_in[4];
    const float* bv1 = (const float*)d_in[5];
    const float* cw2 = (const float*)d_in[6];
    const float* cb2 = (const float*)d_in[7];
    const float* bg2 = (const float*)d_in[8];
    const float* bb2 = (const float*)d_in[9];
    const float* bm2 = (const float*)d_in[10];
    const float* bv2 = (const float*)d_in[11];
    const float* cw3 = (const float*)d_in[12];
    const float* cb3 = (const float*)d_in[13];
    float* out = (float*)d_out;

    hipLaunchKernelGGL(repsurf_fused, dim3(NB * (NP / QPB)), dim3(128), 0, stream,
                       x, cw1, bg1, bb1, bm1, bv1, cw2, cb2, bg2, bb2, bm2, bv2,
                       cw3, cb3, out);
}